// Round 1
// baseline (2288.886 us; speedup 1.0000x reference)
//
#include <hip/hip_runtime.h>

#define NQ    2000      // B*L
#define KDIM  8192      // G*P*ch = 4*32*64
#define EMB   256

__device__ __forceinline__ float sigf(float x) { return 1.0f / (1.0f + __expf(-x)); }

// ---------------------------------------------------------------------------
// Kernel 1: per-query MLPs + sampling-geometry precompute.
// qdata layout per query (1024 floats):
//   [0..127]   px[p]            (pixel coords)
//   [128..255] py[p]
//   [256..767] w[p][4] = lvl_w * sa   (level weight premultiplied by sa gate)
//   [768..1023] ca[256]
// ---------------------------------------------------------------------------
__global__ __launch_bounds__(256) void prep_kernel(
    const float* __restrict__ qc,      // (NQ,256)
    const float* __restrict__ xyzrt,   // (NQ,5)
    const float* __restrict__ Woff,    // (256,384)
    const float* __restrict__ boff,    // (384)
    const float* __restrict__ Wca1,    // (256,64)
    const float* __restrict__ Wca2,    // (64,256)
    const float* __restrict__ Wsa1,    // (256,64)
    const float* __restrict__ Wsa2,    // (64,128)
    float* __restrict__ qdata)         // (NQ,1024)
{
    const int q = blockIdx.x;
    const int t = threadIdx.x;
    __shared__ float qs[256];
    __shared__ float offs[384];
    __shared__ float h1[64];
    __shared__ float h2[64];
    __shared__ float sas[128];

    qs[t] = qc[(size_t)q * 256 + t];
    __syncthreads();

    // Phase A: 512 K=256 dot products (offset 384, ca-hidden 64, sa-hidden 64)
    for (int item = t; item < 512; item += 256) {
        float acc = 0.f;
        if (item < 384) {
            const float* w = Woff + item;
            #pragma unroll 8
            for (int k = 0; k < 256; k++) acc = fmaf(qs[k], w[(size_t)k * 384], acc);
            offs[item] = acc + boff[item];
        } else if (item < 448) {
            const int j = item - 384;
            const float* w = Wca1 + j;
            #pragma unroll 8
            for (int k = 0; k < 256; k++) acc = fmaf(qs[k], w[(size_t)k * 64], acc);
            h1[j] = fmaxf(acc, 0.f);
        } else {
            const int j = item - 448;
            const float* w = Wsa1 + j;
            #pragma unroll 8
            for (int k = 0; k < 256; k++) acc = fmaf(qs[k], w[(size_t)k * 64], acc);
            h2[j] = fmaxf(acc, 0.f);
        }
    }
    __syncthreads();

    // Phase B: ca[t] and sa[t<128]
    {
        float acc = 0.f;
        #pragma unroll 8
        for (int j = 0; j < 64; j++) acc = fmaf(h1[j], Wca2[(size_t)j * 256 + t], acc);
        float* qd = qdata + (size_t)q * 1024;
        qd[768 + t] = sigf(acc);
        if (t < 128) {
            float a2 = 0.f;
            #pragma unroll 8
            for (int j = 0; j < 64; j++) a2 = fmaf(h2[j], Wsa2[(size_t)j * 128 + t], a2);
            sas[t] = sigf(a2);
        }
    }
    __syncthreads();

    // Phase C: geometry per point p (t<128)
    if (t < 128) {
        const int p = t;
        float* qd = qdata + (size_t)q * 1024;
        const float x  = xyzrt[(size_t)q * 5 + 0];
        const float y  = xyzrt[(size_t)q * 5 + 1];
        const float z  = xyzrt[(size_t)q * 5 + 2];
        const float r  = xyzrt[(size_t)q * 5 + 3];
        const float th = xyzrt[(size_t)q * 5 + 4];
        const float sc  = exp2f(z);
        const float rw  = sc * exp2f(-0.5f * r);   // multiplies offset x
        const float rh  = sc * exp2f( 0.5f * r);   // multiplies offset y
        const float cth = __cosf(th), sth = __sinf(th);
        const float ox = offs[p * 3 + 0] * rw;
        const float oy = offs[p * 3 + 1] * rh;
        qd[p]       = x + cth * ox - sth * oy;     // sample x (pixels)
        qd[128 + p] = y + sth * ox + cth * oy;     // sample y (pixels)
        const float sz = z + offs[p * 3 + 2];
        const float sa = sas[p];
        #pragma unroll
        for (int l = 0; l < 4; l++) {
            const float d = sz - (float)(2 + l);   // log2(strides) = {2,3,4,5}
            qd[256 + p * 4 + l] = sigf(-0.5f * d * d) * sa;   // TAU = 2
        }
    }
}

// ---------------------------------------------------------------------------
// Kernel 2: multi-level bilinear sampling. One wave per (q, g, p); lane = ch.
// X[q][(g*32+p)*64 + c] = ca[g*64+c] * sum_l w[l] * bilinear(value_l, px, py)
// All levels: W*stride = 1024, so ix = px/stride - 0.5, iy = py/stride - 0.5.
// ---------------------------------------------------------------------------
__global__ __launch_bounds__(256) void sample_kernel(
    const float* __restrict__ v0, const float* __restrict__ v1,
    const float* __restrict__ v2, const float* __restrict__ v3,
    const float* __restrict__ qdata,
    float* __restrict__ X)
{
    const int wid  = blockIdx.x * 4 + (threadIdx.x >> 6);
    const int lane = threadIdx.x & 63;
    const int q  = wid >> 7;        // /128
    const int gp = wid & 127;
    const int g  = gp >> 5;
    const int b  = (q >= 1000) ? 1 : 0;

    const float* qd = qdata + (size_t)q * 1024;
    const float px = qd[gp];
    const float py = qd[128 + gp];
    const float ca = qd[768 + g * 64 + lane];

    const float* vals[4] = { v0, v1, v2, v3 };
    float acc = 0.f;
    #pragma unroll
    for (int l = 0; l < 4; l++) {
        const float w = qd[256 + gp * 4 + l];
        if (w < 1e-6f) continue;                    // wave-uniform skip
        const int   H = 256 >> l;
        const float inv_stride = 1.0f / (float)(4 << l);
        const float ix = px * inv_stride - 0.5f;
        const float iy = py * inv_stride - 0.5f;
        const float x0f = floorf(ix), y0f = floorf(iy);
        const int   x0 = (int)x0f,    y0 = (int)y0f;
        const float wx1 = ix - x0f, wx0 = 1.f - wx1;
        const float wy1 = iy - y0f, wy0 = 1.f - wy1;
        const bool x0i = (x0 >= 0) && (x0 < H);
        const bool x1i = (x0 + 1 >= 0) && (x0 + 1 < H);
        const bool y0i = (y0 >= 0) && (y0 < H);
        const bool y1i = (y0 + 1 >= 0) && (y0 + 1 < H);
        const float* base = vals[l] + ((size_t)(b * 256 + g * 64 + lane)) * H * H;
        float s = 0.f;
        if (y0i) {
            const float* row = base + (size_t)y0 * H;
            if (x0i) s = fmaf(wx0 * wy0, row[x0], s);
            if (x1i) s = fmaf(wx1 * wy0, row[x0 + 1], s);
        }
        if (y1i) {
            const float* row = base + (size_t)(y0 + 1) * H;
            if (x0i) s = fmaf(wx0 * wy1, row[x0], s);
            if (x1i) s = fmaf(wx1 * wy1, row[x0 + 1], s);
        }
        acc = fmaf(w, s, acc);
    }
    X[(size_t)q * KDIM + gp * 64 + lane] = acc * ca;
}

// ---------------------------------------------------------------------------
// Kernel 3: out = X(2000x8192) @ Wout(8192x256) + bias + query_content
// fp32 tiled 64x64, BK=16, 256 threads, 4x4 per thread, float4 LDS fragments.
// ---------------------------------------------------------------------------
#define BM 64
#define BN 64
#define BK 16

__global__ __launch_bounds__(256) void gemm_kernel(
    const float* __restrict__ X,
    const float* __restrict__ W,       // (8192,256)
    const float* __restrict__ bias,    // (256)
    const float* __restrict__ qc,      // (2000,256)
    float* __restrict__ out)           // (2000,256)
{
    __shared__ float As[BK][BM + 4];   // +4 pad: write banks (4k+m)%32 -> 2-way max
    __shared__ float Bs[BK][BN];
    const int m0 = blockIdx.x * BM;
    const int n0 = blockIdx.y * BN;
    const int t  = threadIdx.x;
    const int tx = t & 15;             // n quadrant
    const int ty = t >> 4;             // m quadrant
    const int ka = t & 15;             // A-load k
    const int ma = t >> 4;             // A-load m base
    const int nb = t & 63;             // B-load n
    const int kb = t >> 6;             // B-load k base

    float acc[4][4] = {};

    for (int k0 = 0; k0 < KDIM; k0 += BK) {
        #pragma unroll
        for (int i = 0; i < 4; i++) {
            const int m   = ma + 16 * i;
            const int row = m0 + m;
            float v = 0.f;
            if (row < NQ) v = X[(size_t)row * KDIM + k0 + ka];
            As[ka][m] = v;
        }
        #pragma unroll
        for (int i = 0; i < 4; i++) {
            const int k = kb + 4 * i;
            Bs[k][nb] = W[(size_t)(k0 + k) * EMB + n0 + nb];
        }
        __syncthreads();
        #pragma unroll
        for (int k = 0; k < BK; k++) {
            const float4 a = *(const float4*)&As[k][ty * 4];
            const float4 bq = *(const float4*)&Bs[k][tx * 4];
            const float av[4] = { a.x, a.y, a.z, a.w };
            const float bv[4] = { bq.x, bq.y, bq.z, bq.w };
            #pragma unroll
            for (int i = 0; i < 4; i++)
                #pragma unroll
                for (int j = 0; j < 4; j++)
                    acc[i][j] = fmaf(av[i], bv[j], acc[i][j]);
        }
        __syncthreads();
    }

    #pragma unroll
    for (int i = 0; i < 4; i++) {
        const int m = m0 + ty * 4 + i;
        if (m >= NQ) continue;
        #pragma unroll
        for (int j = 0; j < 4; j++) {
            const int n = n0 + tx * 4 + j;
            out[(size_t)m * EMB + n] = acc[i][j] + bias[n] + qc[(size_t)m * EMB + n];
        }
    }
}

// ---------------------------------------------------------------------------
extern "C" void kernel_launch(void* const* d_in, const int* in_sizes, int n_in,
                              void* d_out, int out_size, void* d_ws, size_t ws_size,
                              hipStream_t stream) {
    (void)in_sizes; (void)n_in; (void)out_size; (void)ws_size;
    const float* v0    = (const float*)d_in[0];
    const float* v1    = (const float*)d_in[1];
    const float* v2    = (const float*)d_in[2];
    const float* v3    = (const float*)d_in[3];
    const float* qc    = (const float*)d_in[4];
    const float* xyzrt = (const float*)d_in[5];
    // d_in[6] = strides (fixed {4,8,16,32}; hardcoded in kernels)
    const float* Woff  = (const float*)d_in[7];
    const float* boff  = (const float*)d_in[8];
    const float* Wca1  = (const float*)d_in[9];
    const float* Wca2  = (const float*)d_in[10];
    const float* Wsa1  = (const float*)d_in[11];
    const float* Wsa2  = (const float*)d_in[12];
    const float* Wout  = (const float*)d_in[13];
    const float* bout  = (const float*)d_in[14];
    float* out = (float*)d_out;

    float* qdata = (float*)d_ws;                    // NQ*1024 floats = 8.19 MB
    float* X     = qdata + (size_t)NQ * 1024;       // NQ*8192 floats = 65.5 MB

    prep_kernel<<<NQ, 256, 0, stream>>>(qc, xyzrt, Woff, boff, Wca1, Wca2, Wsa1, Wsa2, qdata);
    sample_kernel<<<(NQ * 128) / 4, 256, 0, stream>>>(v0, v1, v2, v3, qdata, X);
    gemm_kernel<<<dim3((NQ + BM - 1) / BM, EMB / BN), 256, 0, stream>>>(X, Wout, bout, qc, out);
}

// Round 2
// 568.131 us; speedup vs baseline: 4.0288x; 4.0288x over previous
//
#include <hip/hip_runtime.h>

#define NQ    2000      // B*L
#define KDIM  8192      // G*P*ch = 4*32*64
#define EMB   256
#define MPAD  2048      // NQ padded for GEMM tiles

typedef __attribute__((ext_vector_type(8))) short bf16x8;
typedef __attribute__((ext_vector_type(4))) float f32x4;

__device__ __forceinline__ float sigf(float x) { return 1.0f / (1.0f + __expf(-x)); }

__device__ __forceinline__ unsigned short f2bf(float x) {
    union { float f; unsigned int u; } v; v.f = x;
    unsigned int r = v.u + 0x7fffu + ((v.u >> 16) & 1u);
    return (unsigned short)(r >> 16);
}
__device__ __forceinline__ float bf2f(unsigned short h) {
    union { unsigned int u; float f; } v; v.u = ((unsigned int)h) << 16; return v.f;
}

// ---------------------------------------------------------------------------
// Kernel 1: per-query MLPs + sampling-geometry precompute. (unchanged from R0)
// qdata layout per query (1024 floats):
//   [0..127] px | [128..255] py | [256..767] w[p][4]=lvl_w*sa | [768..1023] ca
// ---------------------------------------------------------------------------
__global__ __launch_bounds__(256) void prep_kernel(
    const float* __restrict__ qc, const float* __restrict__ xyzrt,
    const float* __restrict__ Woff, const float* __restrict__ boff,
    const float* __restrict__ Wca1, const float* __restrict__ Wca2,
    const float* __restrict__ Wsa1, const float* __restrict__ Wsa2,
    float* __restrict__ qdata)
{
    const int q = blockIdx.x;
    const int t = threadIdx.x;
    __shared__ float qs[256];
    __shared__ float offs[384];
    __shared__ float h1[64];
    __shared__ float h2[64];
    __shared__ float sas[128];

    qs[t] = qc[(size_t)q * 256 + t];
    __syncthreads();

    for (int item = t; item < 512; item += 256) {
        float acc = 0.f;
        if (item < 384) {
            const float* w = Woff + item;
            #pragma unroll 8
            for (int k = 0; k < 256; k++) acc = fmaf(qs[k], w[(size_t)k * 384], acc);
            offs[item] = acc + boff[item];
        } else if (item < 448) {
            const int j = item - 384;
            const float* w = Wca1 + j;
            #pragma unroll 8
            for (int k = 0; k < 256; k++) acc = fmaf(qs[k], w[(size_t)k * 64], acc);
            h1[j] = fmaxf(acc, 0.f);
        } else {
            const int j = item - 448;
            const float* w = Wsa1 + j;
            #pragma unroll 8
            for (int k = 0; k < 256; k++) acc = fmaf(qs[k], w[(size_t)k * 64], acc);
            h2[j] = fmaxf(acc, 0.f);
        }
    }
    __syncthreads();

    {
        float acc = 0.f;
        #pragma unroll 8
        for (int j = 0; j < 64; j++) acc = fmaf(h1[j], Wca2[(size_t)j * 256 + t], acc);
        float* qd = qdata + (size_t)q * 1024;
        qd[768 + t] = sigf(acc);
        if (t < 128) {
            float a2 = 0.f;
            #pragma unroll 8
            for (int j = 0; j < 64; j++) a2 = fmaf(h2[j], Wsa2[(size_t)j * 128 + t], a2);
            sas[t] = sigf(a2);
        }
    }
    __syncthreads();

    if (t < 128) {
        const int p = t;
        float* qd = qdata + (size_t)q * 1024;
        const float x  = xyzrt[(size_t)q * 5 + 0];
        const float y  = xyzrt[(size_t)q * 5 + 1];
        const float z  = xyzrt[(size_t)q * 5 + 2];
        const float r  = xyzrt[(size_t)q * 5 + 3];
        const float th = xyzrt[(size_t)q * 5 + 4];
        const float sc  = exp2f(z);
        const float rw  = sc * exp2f(-0.5f * r);
        const float rh  = sc * exp2f( 0.5f * r);
        const float cth = __cosf(th), sth = __sinf(th);
        const float ox = offs[p * 3 + 0] * rw;
        const float oy = offs[p * 3 + 1] * rh;
        qd[p]       = x + cth * ox - sth * oy;
        qd[128 + p] = y + sth * ox + cth * oy;
        const float sz = z + offs[p * 3 + 2];
        const float sa = sas[p];
        #pragma unroll
        for (int l = 0; l < 4; l++) {
            const float d = sz - (float)(2 + l);
            qd[256 + p * 4 + l] = sigf(-0.5f * d * d) * sa;
        }
    }
}

// ---------------------------------------------------------------------------
// Kernel T: BCHW fp32 -> BHWC bf16 transpose for one level.
// grid = 2(batch) * 4(c-tiles of 64) * (H/32)(x-tiles) * H(y), 256 thr.
// ---------------------------------------------------------------------------
__global__ __launch_bounds__(256) void transpose_kernel(
    const float* __restrict__ v, unsigned short* __restrict__ vt, int H)
{
    int bid = blockIdx.x;
    const int y  = bid % H;            bid /= H;
    const int xt = bid % (H >> 5);     bid /= (H >> 5);
    const int ct = bid & 3;
    const int b  = bid >> 2;
    const int t  = threadIdx.x;

    __shared__ float tile[64][33];
    const float* src = v + ((size_t)(b * 256 + ct * 64) * H + y) * H + xt * 32;
    const int xi = t & 31;
    #pragma unroll
    for (int i = 0; i < 8; i++) {
        const int c = (t >> 5) + i * 8;
        tile[c][xi] = src[(size_t)c * H * H + xi];
    }
    __syncthreads();
    unsigned short* dst = vt + (((size_t)(b * H + y) * H + xt * 32) * 256) + ct * 64;
    const int ci = (t & 31) * 2;
    #pragma unroll
    for (int i = 0; i < 4; i++) {
        const int x2 = (t >> 5) + i * 8;
        ushort2 pk;
        pk.x = f2bf(tile[ci][x2]);
        pk.y = f2bf(tile[ci + 1][x2]);
        *(ushort2*)(dst + (size_t)x2 * 256 + ci) = pk;
    }
}

// ---------------------------------------------------------------------------
// Kernel W: W(8192,256) fp32 -> Wt(256,8192) bf16 transpose.
// grid = (8192/32)*(256/32) = 2048 blocks.
// ---------------------------------------------------------------------------
__global__ __launch_bounds__(256) void wconvert_kernel(
    const float* __restrict__ W, unsigned short* __restrict__ Wt)
{
    const int kt = blockIdx.x & 255;
    const int nt = blockIdx.x >> 8;
    const int k0 = kt * 32, n0 = nt * 32;
    const int t = threadIdx.x;
    __shared__ float tile[32][33];
    #pragma unroll
    for (int i = 0; i < 4; i++) {
        const int ki = (t >> 5) + i * 8;
        tile[ki][t & 31] = W[(size_t)(k0 + ki) * 256 + n0 + (t & 31)];
    }
    __syncthreads();
    #pragma unroll
    for (int i = 0; i < 4; i++) {
        const int ni = (t >> 5) + i * 8;
        const int ki = t & 31;
        Wt[(size_t)(n0 + ni) * KDIM + k0 + ki] = f2bf(tile[ki][ni]);
    }
}

// ---------------------------------------------------------------------------
// Kernel 2: multi-level bilinear sampling from BHWC bf16. One wave per
// (q,g,p), lane = channel. Writes X as bf16 (row-padded to MPAD for GEMM).
// ---------------------------------------------------------------------------
__global__ __launch_bounds__(256) void sample_kernel(
    const unsigned short* __restrict__ v0, const unsigned short* __restrict__ v1,
    const unsigned short* __restrict__ v2, const unsigned short* __restrict__ v3,
    const float* __restrict__ qdata,
    unsigned short* __restrict__ X)
{
    const int wid  = blockIdx.x * 4 + (threadIdx.x >> 6);
    const int lane = threadIdx.x & 63;
    const int q  = wid >> 7;
    const int gp = wid & 127;
    const int g  = gp >> 5;
    const int b  = (q >= 1000) ? 1 : 0;

    const float* qd = qdata + (size_t)q * 1024;
    const float px = qd[gp];
    const float py = qd[128 + gp];
    const float ca = qd[768 + g * 64 + lane];

    const unsigned short* vals[4] = { v0, v1, v2, v3 };
    const int coff = g * 64 + lane;
    float acc = 0.f;
    #pragma unroll
    for (int l = 0; l < 4; l++) {
        const float w = qd[256 + gp * 4 + l];
        if (w < 1e-6f) continue;                    // wave-uniform skip
        const int   H = 256 >> l;
        const float inv_stride = 1.0f / (float)(4 << l);
        const float ix = px * inv_stride - 0.5f;
        const float iy = py * inv_stride - 0.5f;
        const float x0f = floorf(ix), y0f = floorf(iy);
        const int   x0 = (int)x0f,    y0 = (int)y0f;
        const float wx1 = ix - x0f, wx0 = 1.f - wx1;
        const float wy1 = iy - y0f, wy0 = 1.f - wy1;
        const bool x0i = (x0 >= 0) && (x0 < H);
        const bool x1i = (x0 + 1 >= 0) && (x0 + 1 < H);
        const bool y0i = (y0 >= 0) && (y0 < H);
        const bool y1i = (y0 + 1 >= 0) && (y0 + 1 < H);
        const unsigned short* base = vals[l] + (size_t)b * H * H * 256 + coff;
        float s = 0.f;
        if (y0i) {
            const unsigned short* row = base + (size_t)y0 * H * 256;
            if (x0i) s = fmaf(wx0 * wy0, bf2f(row[(size_t)x0 * 256]), s);
            if (x1i) s = fmaf(wx1 * wy0, bf2f(row[(size_t)(x0 + 1) * 256]), s);
        }
        if (y1i) {
            const unsigned short* row = base + (size_t)(y0 + 1) * H * 256;
            if (x0i) s = fmaf(wx0 * wy1, bf2f(row[(size_t)x0 * 256]), s);
            if (x1i) s = fmaf(wx1 * wy1, bf2f(row[(size_t)(x0 + 1) * 256]), s);
        }
        acc = fmaf(w, s, acc);
    }
    X[(size_t)q * KDIM + gp * 64 + lane] = f2bf(acc * ca);
}

// ---------------------------------------------------------------------------
// Kernel 3: partials[z] = X(MPAD x 8192) @ Wt(256 x 8192)^T  via bf16 MFMA.
// 64x64 tile / block, split-K=4 via blockIdx.z, 4 waves each 32x32 (2x2 mfma).
// A-frag: A[m=lane&15][k=quad*8+j]; B-frag: B[k=quad*8+j][n=lane&15];
// D: row=quad*4+reg, col=lane&15  (verified layouts, learn_hip m89/m120).
// ---------------------------------------------------------------------------
#define LSTR 56   // LDS row stride in bf16 (112 B: 16B-aligned, 28-word skew)

__global__ __launch_bounds__(256) void gemm_kernel(
    const unsigned short* __restrict__ X,    // (MPAD, 8192) bf16, rows>=NQ garbage (guarded)
    const unsigned short* __restrict__ Wt,   // (256, 8192) bf16
    float* __restrict__ part)                // (4, MPAD, 256)
{
    __shared__ unsigned short Xs[64][LSTR];
    __shared__ unsigned short Ws[64][LSTR];
    const int m0 = blockIdx.x * 64;
    const int n0 = blockIdx.y * 64;
    const int z  = blockIdx.z;
    const int t  = threadIdx.x;
    const int w    = t >> 6;
    const int lane = t & 63;
    const int mw = (w & 1) * 32;
    const int nw = (w >> 1) * 32;
    const int quad = lane >> 4;
    const int l16  = lane & 15;

    const int srow = t >> 2;            // staging row 0..63
    const int koff = (t & 3) * 8;       // staging k-offset (8 bf16 = 16 B)

    f32x4 acc[2][2] = {};

    const int kbase = z * (KDIM / 4);
    for (int kt = 0; kt < KDIM / 4; kt += 32) {
        const int k0 = kbase + kt;
        {
            const int m = m0 + srow;
            uint4 xv = make_uint4(0, 0, 0, 0);
            if (m < NQ) xv = *(const uint4*)(X + (size_t)m * KDIM + k0 + koff);
            *(uint4*)&Xs[srow][koff] = xv;
            *(uint4*)&Ws[srow][koff] = *(const uint4*)(Wt + (size_t)(n0 + srow) * KDIM + k0 + koff);
        }
        __syncthreads();
        bf16x8 a0 = *(const bf16x8*)&Xs[mw + l16     ][quad * 8];
        bf16x8 a1 = *(const bf16x8*)&Xs[mw + l16 + 16][quad * 8];
        bf16x8 b0 = *(const bf16x8*)&Ws[nw + l16     ][quad * 8];
        bf16x8 b1 = *(const bf16x8*)&Ws[nw + l16 + 16][quad * 8];
        acc[0][0] = __builtin_amdgcn_mfma_f32_16x16x32_bf16(a0, b0, acc[0][0], 0, 0, 0);
        acc[0][1] = __builtin_amdgcn_mfma_f32_16x16x32_bf16(a0, b1, acc[0][1], 0, 0, 0);
        acc[1][0] = __builtin_amdgcn_mfma_f32_16x16x32_bf16(a1, b0, acc[1][0], 0, 0, 0);
        acc[1][1] = __builtin_amdgcn_mfma_f32_16x16x32_bf16(a1, b1, acc[1][1], 0, 0, 0);
        __syncthreads();
    }

    float* pz = part + (size_t)z * MPAD * EMB;
    #pragma unroll
    for (int i = 0; i < 2; i++) {
        #pragma unroll
        for (int j = 0; j < 2; j++) {
            const int n = n0 + nw + 16 * j + l16;
            #pragma unroll
            for (int r = 0; r < 4; r++) {
                const int m = m0 + mw + 16 * i + quad * 4 + r;
                pz[(size_t)m * EMB + n] = acc[i][j][r];
            }
        }
    }
}

// ---------------------------------------------------------------------------
// Kernel 4: out = sum_z part[z] + bias + qc   (fp32, float4)
// ---------------------------------------------------------------------------
__global__ __launch_bounds__(256) void reduce_kernel(
    const float* __restrict__ part, const float* __restrict__ qc,
    const float* __restrict__ bias, float* __restrict__ out)
{
    const int idx = blockIdx.x * 256 + threadIdx.x;   // over NQ*64 float4
    if (idx >= NQ * 64) return;
    const int m  = idx >> 6;
    const int c4 = idx & 63;
    float4 a = ((const float4*)bias)[c4];
    const float4 qv = ((const float4*)qc)[(size_t)m * 64 + c4];
    a.x += qv.x; a.y += qv.y; a.z += qv.z; a.w += qv.w;
    #pragma unroll
    for (int z = 0; z < 4; z++) {
        const float4 p = ((const float4*)part)[((size_t)z * MPAD + m) * 64 + c4];
        a.x += p.x; a.y += p.y; a.z += p.z; a.w += p.w;
    }
    ((float4*)out)[(size_t)m * 64 + c4] = a;
}

// ---------------------------------------------------------------------------
extern "C" void kernel_launch(void* const* d_in, const int* in_sizes, int n_in,
                              void* d_out, int out_size, void* d_ws, size_t ws_size,
                              hipStream_t stream) {
    (void)in_sizes; (void)n_in; (void)out_size; (void)ws_size;
    const float* v0    = (const float*)d_in[0];
    const float* v1    = (const float*)d_in[1];
    const float* v2    = (const float*)d_in[2];
    const float* v3    = (const float*)d_in[3];
    const float* qc    = (const float*)d_in[4];
    const float* xyzrt = (const float*)d_in[5];
    const float* Woff  = (const float*)d_in[7];
    const float* boff  = (const float*)d_in[8];
    const float* Wca1  = (const float*)d_in[9];
    const float* Wca2  = (const float*)d_in[10];
    const float* Wsa1  = (const float*)d_in[11];
    const float* Wsa2  = (const float*)d_in[12];
    const float* Wout  = (const float*)d_in[13];
    const float* bout  = (const float*)d_in[14];
    float* out = (float*)d_out;

    // ws layout (bytes):
    char* p = (char*)d_ws;
    float* qdata = (float*)p;                 p += (size_t)NQ * 1024 * 4;        //  8.19 MB
    unsigned short* Xb = (unsigned short*)p;  p += (size_t)NQ * KDIM * 2;        // 32.77 MB
    unsigned short* vt0 = (unsigned short*)p; p += (size_t)2 * 256 * 256 * 256 * 2; // 67.1 MB
    unsigned short* vt1 = (unsigned short*)p; p += (size_t)2 * 128 * 128 * 256 * 2; // 16.8 MB
    unsigned short* vt2 = (unsigned short*)p; p += (size_t)2 * 64 * 64 * 256 * 2;   //  4.2 MB
    unsigned short* vt3 = (unsigned short*)p; p += (size_t)2 * 32 * 32 * 256 * 2;   //  1.05 MB
    unsigned short* Wtb = (unsigned short*)p; p += (size_t)EMB * KDIM * 2;          //  4.2 MB
    float* partb = (float*)p;                 /* 4*MPAD*256*4 = 8.39 MB */

    prep_kernel<<<NQ, 256, 0, stream>>>(qc, xyzrt, Woff, boff, Wca1, Wca2, Wsa1, Wsa2, qdata);
    transpose_kernel<<<2 * 4 * (256 / 32) * 256, 256, 0, stream>>>(v0, vt0, 256);
    transpose_kernel<<<2 * 4 * (128 / 32) * 128, 256, 0, stream>>>(v1, vt1, 128);
    transpose_kernel<<<2 * 4 * (64 / 32) * 64,   256, 0, stream>>>(v2, vt2, 64);
    transpose_kernel<<<2 * 4 * (32 / 32) * 32,   256, 0, stream>>>(v3, vt3, 32);
    wconvert_kernel<<<2048, 256, 0, stream>>>(Wout, Wtb);
    sample_kernel<<<(NQ * 128) / 4, 256, 0, stream>>>(vt0, vt1, vt2, vt3, qdata, Xb);
    gemm_kernel<<<dim3(MPAD / 64, EMB / 64, 4), 256, 0, stream>>>(Xb, Wtb, partb);
    reduce_kernel<<<(NQ * 64 + 255) / 256, 256, 0, stream>>>(partb, qc, bout, out);
}

// Round 3
// 391.905 us; speedup vs baseline: 5.8404x; 1.4497x over previous
//
#include <hip/hip_runtime.h>

#define NQ    2000      // B*L
#define KDIM  8192      // G*P*ch = 4*32*64
#define EMB   256
#define MPAD  2048      // NQ padded for GEMM tiles
#define SPLITK 8

typedef __attribute__((ext_vector_type(8))) short bf16x8;
typedef __attribute__((ext_vector_type(4))) float f32x4;

__device__ __forceinline__ float sigf(float x) { return 1.0f / (1.0f + __expf(-x)); }

__device__ __forceinline__ unsigned short f2bf(float x) {
    union { float f; unsigned int u; } v; v.f = x;
    unsigned int r = v.u + 0x7fffu + ((v.u >> 16) & 1u);
    return (unsigned short)(r >> 16);
}

// ---------------------------------------------------------------------------
// Kernel 1: per-query MLPs + sampling-geometry precompute.
// qdata layout per query (1024 floats):
//   [0..127] px | [128..255] py | [256..767] w[p][4]=lvl_w*sa | [768..1023] ca
// ---------------------------------------------------------------------------
__global__ __launch_bounds__(256) void prep_kernel(
    const float* __restrict__ qc, const float* __restrict__ xyzrt,
    const float* __restrict__ Woff, const float* __restrict__ boff,
    const float* __restrict__ Wca1, const float* __restrict__ Wca2,
    const float* __restrict__ Wsa1, const float* __restrict__ Wsa2,
    float* __restrict__ qdata)
{
    const int q = blockIdx.x;
    const int t = threadIdx.x;
    __shared__ float qs[256];
    __shared__ float offs[384];
    __shared__ float h1[64];
    __shared__ float h2[64];
    __shared__ float sas[128];

    qs[t] = qc[(size_t)q * 256 + t];
    __syncthreads();

    for (int item = t; item < 512; item += 256) {
        float acc = 0.f;
        if (item < 384) {
            const float* w = Woff + item;
            #pragma unroll 8
            for (int k = 0; k < 256; k++) acc = fmaf(qs[k], w[(size_t)k * 384], acc);
            offs[item] = acc + boff[item];
        } else if (item < 448) {
            const int j = item - 384;
            const float* w = Wca1 + j;
            #pragma unroll 8
            for (int k = 0; k < 256; k++) acc = fmaf(qs[k], w[(size_t)k * 64], acc);
            h1[j] = fmaxf(acc, 0.f);
        } else {
            const int j = item - 448;
            const float* w = Wsa1 + j;
            #pragma unroll 8
            for (int k = 0; k < 256; k++) acc = fmaf(qs[k], w[(size_t)k * 64], acc);
            h2[j] = fmaxf(acc, 0.f);
        }
    }
    __syncthreads();

    {
        float acc = 0.f;
        #pragma unroll 8
        for (int j = 0; j < 64; j++) acc = fmaf(h1[j], Wca2[(size_t)j * 256 + t], acc);
        float* qd = qdata + (size_t)q * 1024;
        qd[768 + t] = sigf(acc);
        if (t < 128) {
            float a2 = 0.f;
            #pragma unroll 8
            for (int j = 0; j < 64; j++) a2 = fmaf(h2[j], Wsa2[(size_t)j * 128 + t], a2);
            sas[t] = sigf(a2);
        }
    }
    __syncthreads();

    if (t < 128) {
        const int p = t;
        float* qd = qdata + (size_t)q * 1024;
        const float x  = xyzrt[(size_t)q * 5 + 0];
        const float y  = xyzrt[(size_t)q * 5 + 1];
        const float z  = xyzrt[(size_t)q * 5 + 2];
        const float r  = xyzrt[(size_t)q * 5 + 3];
        const float th = xyzrt[(size_t)q * 5 + 4];
        const float sc  = exp2f(z);
        const float rw  = sc * exp2f(-0.5f * r);
        const float rh  = sc * exp2f( 0.5f * r);
        const float cth = __cosf(th), sth = __sinf(th);
        const float ox = offs[p * 3 + 0] * rw;
        const float oy = offs[p * 3 + 1] * rh;
        qd[p]       = x + cth * ox - sth * oy;
        qd[128 + p] = y + sth * ox + cth * oy;
        const float sz = z + offs[p * 3 + 2];
        const float sa = sas[p];
        #pragma unroll
        for (int l = 0; l < 4; l++) {
            const float d = sz - (float)(2 + l);
            qd[256 + p * 4 + l] = sigf(-0.5f * d * d) * sa;
        }
    }
}

// ---------------------------------------------------------------------------
// Kernel T: BCHW fp32 -> BHWC bf16 transpose for one level.
// grid = 2(batch) * 4(c-tiles of 64) * (H/32)(x-tiles) * H(y), 256 thr.
// ---------------------------------------------------------------------------
__global__ __launch_bounds__(256) void transpose_kernel(
    const float* __restrict__ v, unsigned short* __restrict__ vt, int H)
{
    int bid = blockIdx.x;
    const int y  = bid % H;            bid /= H;
    const int xt = bid % (H >> 5);     bid /= (H >> 5);
    const int ct = bid & 3;
    const int b  = bid >> 2;
    const int t  = threadIdx.x;

    __shared__ float tile[64][33];
    const float* src = v + ((size_t)(b * 256 + ct * 64) * H + y) * H + xt * 32;
    const int xi = t & 31;
    #pragma unroll
    for (int i = 0; i < 8; i++) {
        const int c = (t >> 5) + i * 8;
        tile[c][xi] = src[(size_t)c * H * H + xi];
    }
    __syncthreads();
    unsigned short* dst = vt + (((size_t)(b * H + y) * H + xt * 32) * 256) + ct * 64;
    const int ci = (t & 31) * 2;
    #pragma unroll
    for (int i = 0; i < 4; i++) {
        const int x2 = (t >> 5) + i * 8;
        ushort2 pk;
        pk.x = f2bf(tile[ci][x2]);
        pk.y = f2bf(tile[ci + 1][x2]);
        *(ushort2*)(dst + (size_t)x2 * 256 + ci) = pk;
    }
}

// ---------------------------------------------------------------------------
// Kernel W: W(8192,256) fp32 -> Wt(256,8192) bf16 transpose.
// ---------------------------------------------------------------------------
__global__ __launch_bounds__(256) void wconvert_kernel(
    const float* __restrict__ W, unsigned short* __restrict__ Wt)
{
    const int kt = blockIdx.x & 255;
    const int nt = blockIdx.x >> 8;
    const int k0 = kt * 32, n0 = nt * 32;
    const int t = threadIdx.x;
    __shared__ float tile[32][33];
    #pragma unroll
    for (int i = 0; i < 4; i++) {
        const int ki = (t >> 5) + i * 8;
        tile[ki][t & 31] = W[(size_t)(k0 + ki) * 256 + n0 + (t & 31)];
    }
    __syncthreads();
    #pragma unroll
    for (int i = 0; i < 4; i++) {
        const int ni = (t >> 5) + i * 8;
        const int ki = t & 31;
        Wt[(size_t)(n0 + ni) * KDIM + k0 + ki] = f2bf(tile[ki][ni]);
    }
}

// ---------------------------------------------------------------------------
// Kernel 2: vectorized multi-level bilinear sampling from BHWC bf16.
// One wave = 8 points x 64 ch; lane = (pt = lane>>3, c8 = (lane&7)*8).
// Each tap: one global_load_dwordx4 (16B/lane, 1KB/wave). Branchless
// clamped coords + masked weights. Output: coalesced ushort8/lane.
// ---------------------------------------------------------------------------
__global__ __launch_bounds__(256) void sample_kernel(
    const unsigned short* __restrict__ v0, const unsigned short* __restrict__ v1,
    const unsigned short* __restrict__ v2, const unsigned short* __restrict__ v3,
    const float* __restrict__ qdata,
    unsigned short* __restrict__ X)
{
    const int wid  = blockIdx.x * 4 + (threadIdx.x >> 6);
    const int lane = threadIdx.x & 63;
    const int q  = wid >> 4;           // 16 waves per query
    const int pb = (wid & 15) * 8;     // base gp of this wave
    const int pt = lane >> 3;          // point within wave 0..7
    const int gp = pb + pt;
    const int g  = gp >> 5;
    const int c8 = (lane & 7) * 8;     // channel offset within group
    const int b  = (q >= 1000) ? 1 : 0;

    const float* qd = qdata + (size_t)q * 1024;
    const float px = qd[gp];
    const float py = qd[128 + gp];
    float wlv[4];
    #pragma unroll
    for (int l = 0; l < 4; l++) wlv[l] = qd[256 + gp * 4 + l];

    const unsigned short* vals[4] = { v0, v1, v2, v3 };
    const int cbase = g * 64 + c8;

    float acc[8] = {};
    #pragma unroll
    for (int l = 0; l < 4; l++) {
        const int   H   = 256 >> l;
        const float inv = 1.0f / (float)(4 << l);
        const float wl  = wlv[l];
        const float ix = px * inv - 0.5f;
        const float iy = py * inv - 0.5f;
        const float x0f = floorf(ix), y0f = floorf(iy);
        const int   x0 = (int)x0f,    y0 = (int)y0f;
        const float fx1 = ix - x0f, fx0 = 1.f - fx1;
        const float fy1 = iy - y0f, fy0 = 1.f - fy1;
        const bool xi0 = (x0 >= 0) & (x0 < H);
        const bool xi1 = (x0 + 1 >= 0) & (x0 + 1 < H);
        const bool yi0 = (y0 >= 0) & (y0 < H);
        const bool yi1 = (y0 + 1 >= 0) & (y0 + 1 < H);
        const int xc0 = min(max(x0, 0), H - 1);
        const int xc1 = min(max(x0 + 1, 0), H - 1);
        const int yc0 = min(max(y0, 0), H - 1);
        const int yc1 = min(max(y0 + 1, 0), H - 1);
        const float m00 = (xi0 & yi0) ? wl * fx0 * fy0 : 0.f;
        const float m10 = (xi1 & yi0) ? wl * fx1 * fy0 : 0.f;
        const float m01 = (xi0 & yi1) ? wl * fx0 * fy1 : 0.f;
        const float m11 = (xi1 & yi1) ? wl * fx1 * fy1 : 0.f;

        const unsigned short* base = vals[l] + (size_t)b * H * H * 256 + cbase;
        const int ry0 = yc0 * H, ry1 = yc1 * H;
        const uint4 d00 = *(const uint4*)(base + (size_t)(ry0 + xc0) * 256);
        const uint4 d10 = *(const uint4*)(base + (size_t)(ry0 + xc1) * 256);
        const uint4 d01 = *(const uint4*)(base + (size_t)(ry1 + xc0) * 256);
        const uint4 d11 = *(const uint4*)(base + (size_t)(ry1 + xc1) * 256);

        const uint4 dv[4] = { d00, d10, d01, d11 };
        const float mv[4] = { m00, m10, m01, m11 };
        #pragma unroll
        for (int tap = 0; tap < 4; tap++) {
            const unsigned int du[4] = { dv[tap].x, dv[tap].y, dv[tap].z, dv[tap].w };
            const float m = mv[tap];
            #pragma unroll
            for (int i = 0; i < 4; i++) {
                union { unsigned int u; float f; } lo, hi;
                lo.u = du[i] << 16;
                hi.u = du[i] & 0xffff0000u;
                acc[2 * i]     = fmaf(m, lo.f, acc[2 * i]);
                acc[2 * i + 1] = fmaf(m, hi.f, acc[2 * i + 1]);
            }
        }
    }

    // ca gate + pack + coalesced store
    const float* caf = qd + 768 + cbase;
    const float4 ca0 = *(const float4*)caf;
    const float4 ca1 = *(const float4*)(caf + 4);
    const float cav[8] = { ca0.x, ca0.y, ca0.z, ca0.w, ca1.x, ca1.y, ca1.z, ca1.w };
    uint4 o;
    unsigned int* op = (unsigned int*)&o;
    #pragma unroll
    for (int i = 0; i < 4; i++) {
        const unsigned int lo = f2bf(acc[2 * i] * cav[2 * i]);
        const unsigned int hi = f2bf(acc[2 * i + 1] * cav[2 * i + 1]);
        op[i] = lo | (hi << 16);
    }
    *(uint4*)(X + (size_t)q * KDIM + pb * 64 + lane * 8) = o;
}

// ---------------------------------------------------------------------------
// Kernel 3: partials[z] = X(MPAD x 8192) @ Wt(256 x 8192)^T  via bf16 MFMA.
// 64x64 tile / block, split-K=8 via blockIdx.z (1024 blocks, 4/CU).
// ---------------------------------------------------------------------------
#define LSTR 56   // LDS row stride in bf16 (112 B: 16B-aligned, 28-word skew)

__global__ __launch_bounds__(256) void gemm_kernel(
    const unsigned short* __restrict__ X,    // (MPAD, 8192) bf16 (rows>=NQ guarded)
    const unsigned short* __restrict__ Wt,   // (256, 8192) bf16
    float* __restrict__ part)                // (SPLITK, MPAD, 256)
{
    __shared__ unsigned short Xs[64][LSTR];
    __shared__ unsigned short Ws[64][LSTR];
    const int m0 = blockIdx.x * 64;
    const int n0 = blockIdx.y * 64;
    const int z  = blockIdx.z;
    const int t  = threadIdx.x;
    const int w    = t >> 6;
    const int lane = t & 63;
    const int mw = (w & 1) * 32;
    const int nw = (w >> 1) * 32;
    const int quad = lane >> 4;
    const int l16  = lane & 15;

    const int srow = t >> 2;
    const int koff = (t & 3) * 8;

    f32x4 acc[2][2] = {};

    const int kbase = z * (KDIM / SPLITK);
    for (int kt = 0; kt < KDIM / SPLITK; kt += 32) {
        const int k0 = kbase + kt;
        {
            const int m = m0 + srow;
            uint4 xv = make_uint4(0, 0, 0, 0);
            if (m < NQ) xv = *(const uint4*)(X + (size_t)m * KDIM + k0 + koff);
            *(uint4*)&Xs[srow][koff] = xv;
            *(uint4*)&Ws[srow][koff] = *(const uint4*)(Wt + (size_t)(n0 + srow) * KDIM + k0 + koff);
        }
        __syncthreads();
        bf16x8 a0 = *(const bf16x8*)&Xs[mw + l16     ][quad * 8];
        bf16x8 a1 = *(const bf16x8*)&Xs[mw + l16 + 16][quad * 8];
        bf16x8 b0 = *(const bf16x8*)&Ws[nw + l16     ][quad * 8];
        bf16x8 b1 = *(const bf16x8*)&Ws[nw + l16 + 16][quad * 8];
        acc[0][0] = __builtin_amdgcn_mfma_f32_16x16x32_bf16(a0, b0, acc[0][0], 0, 0, 0);
        acc[0][1] = __builtin_amdgcn_mfma_f32_16x16x32_bf16(a0, b1, acc[0][1], 0, 0, 0);
        acc[1][0] = __builtin_amdgcn_mfma_f32_16x16x32_bf16(a1, b0, acc[1][0], 0, 0, 0);
        acc[1][1] = __builtin_amdgcn_mfma_f32_16x16x32_bf16(a1, b1, acc[1][1], 0, 0, 0);
        __syncthreads();
    }

    float* pz = part + (size_t)z * MPAD * EMB;
    #pragma unroll
    for (int i = 0; i < 2; i++) {
        #pragma unroll
        for (int j = 0; j < 2; j++) {
            const int n = n0 + nw + 16 * j + l16;
            #pragma unroll
            for (int r = 0; r < 4; r++) {
                const int m = m0 + mw + 16 * i + quad * 4 + r;
                pz[(size_t)m * EMB + n] = acc[i][j][r];
            }
        }
    }
}

// ---------------------------------------------------------------------------
// Kernel 4: out = sum_z part[z] + bias + qc   (fp32, float4)
// ---------------------------------------------------------------------------
__global__ __launch_bounds__(256) void reduce_kernel(
    const float* __restrict__ part, const float* __restrict__ qc,
    const float* __restrict__ bias, float* __restrict__ out)
{
    const int idx = blockIdx.x * 256 + threadIdx.x;   // over NQ*64 float4
    if (idx >= NQ * 64) return;
    const int m  = idx >> 6;
    const int c4 = idx & 63;
    float4 a = ((const float4*)bias)[c4];
    const float4 qv = ((const float4*)qc)[(size_t)m * 64 + c4];
    a.x += qv.x; a.y += qv.y; a.z += qv.z; a.w += qv.w;
    #pragma unroll
    for (int z = 0; z < SPLITK; z++) {
        const float4 p = ((const float4*)part)[((size_t)z * MPAD + m) * 64 + c4];
        a.x += p.x; a.y += p.y; a.z += p.z; a.w += p.w;
    }
    ((float4*)out)[(size_t)m * 64 + c4] = a;
}

// ---------------------------------------------------------------------------
extern "C" void kernel_launch(void* const* d_in, const int* in_sizes, int n_in,
                              void* d_out, int out_size, void* d_ws, size_t ws_size,
                              hipStream_t stream) {
    (void)in_sizes; (void)n_in; (void)out_size; (void)ws_size;
    const float* v0    = (const float*)d_in[0];
    const float* v1    = (const float*)d_in[1];
    const float* v2    = (const float*)d_in[2];
    const float* v3    = (const float*)d_in[3];
    const float* qc    = (const float*)d_in[4];
    const float* xyzrt = (const float*)d_in[5];
    const float* Woff  = (const float*)d_in[7];
    const float* boff  = (const float*)d_in[8];
    const float* Wca1  = (const float*)d_in[9];
    const float* Wca2  = (const float*)d_in[10];
    const float* Wsa1  = (const float*)d_in[11];
    const float* Wsa2  = (const float*)d_in[12];
    const float* Wout  = (const float*)d_in[13];
    const float* bout  = (const float*)d_in[14];
    float* out = (float*)d_out;

    // ws layout (bytes):
    char* p = (char*)d_ws;
    float* qdata = (float*)p;                 p += (size_t)NQ * 1024 * 4;           //  8.19 MB
    unsigned short* Xb = (unsigned short*)p;  p += (size_t)NQ * KDIM * 2;           // 32.77 MB
    unsigned short* vt0 = (unsigned short*)p; p += (size_t)2 * 256 * 256 * 256 * 2; // 67.1 MB
    unsigned short* vt1 = (unsigned short*)p; p += (size_t)2 * 128 * 128 * 256 * 2; // 16.8 MB
    unsigned short* vt2 = (unsigned short*)p; p += (size_t)2 * 64 * 64 * 256 * 2;   //  4.2 MB
    unsigned short* vt3 = (unsigned short*)p; p += (size_t)2 * 32 * 32 * 256 * 2;   //  1.05 MB
    unsigned short* Wtb = (unsigned short*)p; p += (size_t)EMB * KDIM * 2;          //  4.2 MB
    float* partb = (float*)p;                 /* SPLITK*MPAD*256*4 = 16.8 MB */

    prep_kernel<<<NQ, 256, 0, stream>>>(qc, xyzrt, Woff, boff, Wca1, Wca2, Wsa1, Wsa2, qdata);
    transpose_kernel<<<2 * 4 * (256 / 32) * 256, 256, 0, stream>>>(v0, vt0, 256);
    transpose_kernel<<<2 * 4 * (128 / 32) * 128, 256, 0, stream>>>(v1, vt1, 128);
    transpose_kernel<<<2 * 4 * (64 / 32) * 64,   256, 0, stream>>>(v2, vt2, 64);
    transpose_kernel<<<2 * 4 * (32 / 32) * 32,   256, 0, stream>>>(v3, vt3, 32);
    wconvert_kernel<<<2048, 256, 0, stream>>>(Wout, Wtb);
    sample_kernel<<<(NQ * 128) / (4 * 8), 256, 0, stream>>>(vt0, vt1, vt2, vt3, qdata, Xb);
    gemm_kernel<<<dim3(MPAD / 64, EMB / 64, SPLITK), 256, 0, stream>>>(Xb, Wtb, partb);
    reduce_kernel<<<(NQ * 64 + 255) / 256, 256, 0, stream>>>(partb, qc, bout, out);
}

// Round 4
// 388.763 us; speedup vs baseline: 5.8876x; 1.0081x over previous
//
#include <hip/hip_runtime.h>

#define NQ    2000      // B*L
#define KDIM  8192      // G*P*ch = 4*32*64
#define EMB   256
#define MPAD  2048      // NQ padded for GEMM tiles
#define SPLITK 8

typedef __attribute__((ext_vector_type(8))) short bf16x8;
typedef __attribute__((ext_vector_type(4))) float f32x4;

__device__ __forceinline__ float sigf(float x) { return 1.0f / (1.0f + __expf(-x)); }

__device__ __forceinline__ unsigned short f2bf(float x) {
    union { float f; unsigned int u; } v; v.f = x;
    unsigned int r = v.u + 0x7fffu + ((v.u >> 16) & 1u);
    return (unsigned short)(r >> 16);
}
__device__ __forceinline__ float bf2f(unsigned short h) {
    union { unsigned int u; float f; } v; v.u = ((unsigned int)h) << 16; return v.f;
}

// ---------------------------------------------------------------------------
// Kernel T (merged): all one-time layout work in a single launch.
//   region A [0,21760):      BCHW fp32 -> BHWC bf16 transpose, 4 levels
//   region B [21760,23808):  Wout(8192,256) -> Wtb(256,8192) bf16
//   region C [23808,24320):  {Woff|Wca1|Wsa1} -> WH/WL (512,256) double-bf16
//   region D [24320,26368):  qc -> qcH/qcL (2048,256) double-bf16, zero-pad
// ---------------------------------------------------------------------------
__global__ __launch_bounds__(256) void trans_kernel(
    const float* __restrict__ v0, const float* __restrict__ v1,
    const float* __restrict__ v2, const float* __restrict__ v3,
    unsigned short* __restrict__ vt0, unsigned short* __restrict__ vt1,
    unsigned short* __restrict__ vt2, unsigned short* __restrict__ vt3,
    const float* __restrict__ Wout, unsigned short* __restrict__ Wtb,
    const float* __restrict__ Woff, const float* __restrict__ Wca1,
    const float* __restrict__ Wsa1,
    unsigned short* __restrict__ WH, unsigned short* __restrict__ WL,
    const float* __restrict__ qc,
    unsigned short* __restrict__ qcH, unsigned short* __restrict__ qcL)
{
    __shared__ float tile[64][33];
    int bid = blockIdx.x;
    const int t = threadIdx.x;

    if (bid < 21760) {
        const float* v; unsigned short* vt; int H;
        if (bid < 16384)      { v = v0; vt = vt0; H = 256; }
        else if (bid < 20480) { bid -= 16384; v = v1; vt = vt1; H = 128; }
        else if (bid < 21504) { bid -= 20480; v = v2; vt = vt2; H = 64; }
        else                  { bid -= 21504; v = v3; vt = vt3; H = 32; }
        const int y  = bid % H;            bid /= H;
        const int xt = bid % (H >> 5);     bid /= (H >> 5);
        const int ct = bid & 3;
        const int b  = bid >> 2;
        const float* src = v + ((size_t)(b * 256 + ct * 64) * H + y) * H + xt * 32;
        const int xi = t & 31;
        #pragma unroll
        for (int i = 0; i < 8; i++) {
            const int c = (t >> 5) + i * 8;
            tile[c][xi] = src[(size_t)c * H * H + xi];
        }
        __syncthreads();
        unsigned short* dst = vt + (((size_t)(b * H + y) * H + xt * 32) * 256) + ct * 64;
        const int ci = (t & 31) * 2;
        #pragma unroll
        for (int i = 0; i < 4; i++) {
            const int x2 = (t >> 5) + i * 8;
            ushort2 pk;
            pk.x = f2bf(tile[ci][x2]);
            pk.y = f2bf(tile[ci + 1][x2]);
            *(ushort2*)(dst + (size_t)x2 * 256 + ci) = pk;
        }
    } else if (bid < 23808) {
        const int local = bid - 21760;
        const int k0 = (local & 255) * 32, n0 = (local >> 8) * 32;
        float (*tl)[33] = tile;
        #pragma unroll
        for (int i = 0; i < 4; i++) {
            const int ki = (t >> 5) + i * 8;
            tl[ki][t & 31] = Wout[(size_t)(k0 + ki) * 256 + n0 + (t & 31)];
        }
        __syncthreads();
        #pragma unroll
        for (int i = 0; i < 4; i++) {
            const int ni = (t >> 5) + i * 8;
            const int ki = t & 31;
            Wtb[(size_t)(n0 + ni) * KDIM + k0 + ki] = f2bf(tl[ki][ni]);
        }
    } else if (bid < 24320) {
        const int n = bid - 23808;        // 0..511, thread = k
        float val;
        if (n < 384)      val = Woff[(size_t)t * 384 + n];
        else if (n < 448) val = Wca1[(size_t)t * 64 + (n - 384)];
        else              val = Wsa1[(size_t)t * 64 + (n - 448)];
        const unsigned short hh = f2bf(val);
        WH[(size_t)n * 256 + t] = hh;
        WL[(size_t)n * 256 + t] = f2bf(val - bf2f(hh));
    } else {
        const int q = bid - 24320;        // 0..2047
        const float val = (q < NQ) ? qc[(size_t)q * 256 + t] : 0.f;
        const unsigned short hh = f2bf(val);
        qcH[(size_t)q * 256 + t] = hh;
        qcL[(size_t)q * 256 + t] = f2bf(val - bf2f(hh));
    }
}

// ---------------------------------------------------------------------------
// Kernel A: H(2048,512) = qc(2048,256) @ [Woff|Wca1|Wsa1](256,512), fp32-ish
// accuracy via double-bf16 (3 MFMA passes: AH*BH + AH*BL + AL*BH).
// No LDS; fragments loaded directly from global (K-contiguous both sides).
// grid (32, 8), 256 thr = 4 waves, wave = 32x32 quadrant (2x2 of 16x16x32).
// ---------------------------------------------------------------------------
__global__ __launch_bounds__(256) void gemmA_kernel(
    const unsigned short* __restrict__ qcH, const unsigned short* __restrict__ qcL,
    const unsigned short* __restrict__ WH,  const unsigned short* __restrict__ WL,
    float* __restrict__ Hout)               // (2048, 512)
{
    const int m0 = blockIdx.x * 64;
    const int n0 = blockIdx.y * 64;
    const int t  = threadIdx.x;
    const int w    = t >> 6;
    const int lane = t & 63;
    const int mw = (w & 1) * 32;
    const int nw = (w >> 1) * 32;
    const int quad = lane >> 4;
    const int l16  = lane & 15;

    f32x4 acc[2][2] = {};
    #pragma unroll
    for (int pass = 0; pass < 3; pass++) {
        const unsigned short* Ap = (pass == 2) ? qcL : qcH;
        const unsigned short* Bp = (pass == 1) ? WL : WH;
        const unsigned short* ar0 = Ap + (size_t)(m0 + mw + l16) * 256 + quad * 8;
        const unsigned short* ar1 = ar0 + 16 * 256;
        const unsigned short* br0 = Bp + (size_t)(n0 + nw + l16) * 256 + quad * 8;
        const unsigned short* br1 = br0 + 16 * 256;
        #pragma unroll
        for (int k = 0; k < 256; k += 32) {
            const bf16x8 a0 = *(const bf16x8*)(ar0 + k);
            const bf16x8 a1 = *(const bf16x8*)(ar1 + k);
            const bf16x8 b0 = *(const bf16x8*)(br0 + k);
            const bf16x8 b1 = *(const bf16x8*)(br1 + k);
            acc[0][0] = __builtin_amdgcn_mfma_f32_16x16x32_bf16(a0, b0, acc[0][0], 0, 0, 0);
            acc[0][1] = __builtin_amdgcn_mfma_f32_16x16x32_bf16(a0, b1, acc[0][1], 0, 0, 0);
            acc[1][0] = __builtin_amdgcn_mfma_f32_16x16x32_bf16(a1, b0, acc[1][0], 0, 0, 0);
            acc[1][1] = __builtin_amdgcn_mfma_f32_16x16x32_bf16(a1, b1, acc[1][1], 0, 0, 0);
        }
    }
    #pragma unroll
    for (int i = 0; i < 2; i++)
        #pragma unroll
        for (int j = 0; j < 2; j++) {
            const int n = n0 + nw + 16 * j + l16;
            #pragma unroll
            for (int r = 0; r < 4; r++) {
                const int m = m0 + mw + 16 * i + quad * 4 + r;
                Hout[(size_t)m * 512 + n] = acc[i][j][r];
            }
        }
}

// ---------------------------------------------------------------------------
// Kernel F: finish — per 8-query block: ca/sa second-layer dots + sigmoid +
// sampling geometry. Reads H(2048,512): [0,384)=offsets(+boff here),
// [384,448)=ca hidden (relu), [448,512)=sa hidden (relu).
// qdata per query (1024 f): [0,128) px | [128,256) py | [256,768) w[p][4] |
// [768,1024) ca.
// ---------------------------------------------------------------------------
__global__ __launch_bounds__(256) void finish_kernel(
    const float* __restrict__ Hbuf, const float* __restrict__ xyzrt,
    const float* __restrict__ boff,
    const float* __restrict__ Wca2, const float* __restrict__ Wsa2,
    float* __restrict__ qdata)
{
    const int q0 = blockIdx.x * 8;
    const int t  = threadIdx.x;
    __shared__ float hca[8][64];
    __shared__ float hsa[8][64];
    __shared__ float sas[8][128];

    for (int i = t; i < 1024; i += 256) {
        const int q = i >> 7, j = i & 127;
        const float v = fmaxf(Hbuf[(size_t)(q0 + q) * 512 + 384 + j], 0.f);
        if (j < 64) hca[q][j] = v; else hsa[q][j - 64] = v;
    }
    __syncthreads();

    {   // ca: channel c = t, all 8 queries
        float acc[8] = {};
        for (int j = 0; j < 64; j++) {
            const float wv = Wca2[(size_t)j * 256 + t];
            #pragma unroll
            for (int q = 0; q < 8; q++) acc[q] = fmaf(hca[q][j], wv, acc[q]);
        }
        #pragma unroll
        for (int q = 0; q < 8; q++)
            qdata[(size_t)(q0 + q) * 1024 + 768 + t] = sigf(acc[q]);
    }
    {   // sa: c = t&127, 4 queries per thread
        const int c  = t & 127;
        const int qb = (t >> 7) * 4;
        float acc[4] = {};
        for (int j = 0; j < 64; j++) {
            const float wv = Wsa2[(size_t)j * 128 + c];
            #pragma unroll
            for (int qq = 0; qq < 4; qq++) acc[qq] = fmaf(hsa[qb + qq][j], wv, acc[qq]);
        }
        #pragma unroll
        for (int qq = 0; qq < 4; qq++) sas[qb + qq][c] = sigf(acc[qq]);
    }
    __syncthreads();

    {   // geometry: p = t&127, 4 queries per thread
        const int p  = t & 127;
        const int qb = (t >> 7) * 4;
        #pragma unroll
        for (int qq = 0; qq < 4; qq++) {
            const int q = qb + qq;
            const float* hrow = Hbuf + (size_t)(q0 + q) * 512 + p * 3;
            const float o0 = hrow[0] + boff[p * 3 + 0];
            const float o1 = hrow[1] + boff[p * 3 + 1];
            const float o2 = hrow[2] + boff[p * 3 + 2];
            const float* xr = xyzrt + (size_t)(q0 + q) * 5;
            const float x = xr[0], y = xr[1], z = xr[2], r = xr[3], th = xr[4];
            const float sc  = exp2f(z);
            const float rw  = sc * exp2f(-0.5f * r);
            const float rh  = sc * exp2f( 0.5f * r);
            const float cth = __cosf(th), sth = __sinf(th);
            const float ox = o0 * rw;
            const float oy = o1 * rh;
            float* qd = qdata + (size_t)(q0 + q) * 1024;
            qd[p]       = x + cth * ox - sth * oy;
            qd[128 + p] = y + sth * ox + cth * oy;
            const float sz = z + o2;
            const float sa = sas[q][p];
            #pragma unroll
            for (int l = 0; l < 4; l++) {
                const float d = sz - (float)(2 + l);
                qd[256 + p * 4 + l] = sigf(-0.5f * d * d) * sa;
            }
        }
    }
}

// ---------------------------------------------------------------------------
// Kernel 2: vectorized multi-level bilinear sampling from BHWC bf16.
// One wave = 8 points x 64 ch; lane = (pt = lane>>3, c8 = (lane&7)*8).
// ---------------------------------------------------------------------------
__global__ __launch_bounds__(256) void sample_kernel(
    const unsigned short* __restrict__ v0, const unsigned short* __restrict__ v1,
    const unsigned short* __restrict__ v2, const unsigned short* __restrict__ v3,
    const float* __restrict__ qdata,
    unsigned short* __restrict__ X)
{
    const int wid  = blockIdx.x * 4 + (threadIdx.x >> 6);
    const int lane = threadIdx.x & 63;
    const int q  = wid >> 4;
    const int pb = (wid & 15) * 8;
    const int pt = lane >> 3;
    const int gp = pb + pt;
    const int g  = gp >> 5;
    const int c8 = (lane & 7) * 8;
    const int b  = (q >= 1000) ? 1 : 0;

    const float* qd = qdata + (size_t)q * 1024;
    const float px = qd[gp];
    const float py = qd[128 + gp];
    float wlv[4];
    #pragma unroll
    for (int l = 0; l < 4; l++) wlv[l] = qd[256 + gp * 4 + l];

    const unsigned short* vals[4] = { v0, v1, v2, v3 };
    const int cbase = g * 64 + c8;

    float acc[8] = {};
    #pragma unroll
    for (int l = 0; l < 4; l++) {
        const int   H   = 256 >> l;
        const float inv = 1.0f / (float)(4 << l);
        const float wl  = wlv[l];
        const float ix = px * inv - 0.5f;
        const float iy = py * inv - 0.5f;
        const float x0f = floorf(ix), y0f = floorf(iy);
        const int   x0 = (int)x0f,    y0 = (int)y0f;
        const float fx1 = ix - x0f, fx0 = 1.f - fx1;
        const float fy1 = iy - y0f, fy0 = 1.f - fy1;
        const bool xi0 = (x0 >= 0) & (x0 < H);
        const bool xi1 = (x0 + 1 >= 0) & (x0 + 1 < H);
        const bool yi0 = (y0 >= 0) & (y0 < H);
        const bool yi1 = (y0 + 1 >= 0) & (y0 + 1 < H);
        const int xc0 = min(max(x0, 0), H - 1);
        const int xc1 = min(max(x0 + 1, 0), H - 1);
        const int yc0 = min(max(y0, 0), H - 1);
        const int yc1 = min(max(y0 + 1, 0), H - 1);
        const float m00 = (xi0 & yi0) ? wl * fx0 * fy0 : 0.f;
        const float m10 = (xi1 & yi0) ? wl * fx1 * fy0 : 0.f;
        const float m01 = (xi0 & yi1) ? wl * fx0 * fy1 : 0.f;
        const float m11 = (xi1 & yi1) ? wl * fx1 * fy1 : 0.f;

        const unsigned short* base = vals[l] + (size_t)b * H * H * 256 + cbase;
        const int ry0 = yc0 * H, ry1 = yc1 * H;
        const uint4 d00 = *(const uint4*)(base + (size_t)(ry0 + xc0) * 256);
        const uint4 d10 = *(const uint4*)(base + (size_t)(ry0 + xc1) * 256);
        const uint4 d01 = *(const uint4*)(base + (size_t)(ry1 + xc0) * 256);
        const uint4 d11 = *(const uint4*)(base + (size_t)(ry1 + xc1) * 256);

        const uint4 dv[4] = { d00, d10, d01, d11 };
        const float mv[4] = { m00, m10, m01, m11 };
        #pragma unroll
        for (int tap = 0; tap < 4; tap++) {
            const unsigned int du[4] = { dv[tap].x, dv[tap].y, dv[tap].z, dv[tap].w };
            const float m = mv[tap];
            #pragma unroll
            for (int i = 0; i < 4; i++) {
                union { unsigned int u; float f; } lo, hi;
                lo.u = du[i] << 16;
                hi.u = du[i] & 0xffff0000u;
                acc[2 * i]     = fmaf(m, lo.f, acc[2 * i]);
                acc[2 * i + 1] = fmaf(m, hi.f, acc[2 * i + 1]);
            }
        }
    }

    const float* caf = qd + 768 + cbase;
    const float4 ca0 = *(const float4*)caf;
    const float4 ca1 = *(const float4*)(caf + 4);
    const float cav[8] = { ca0.x, ca0.y, ca0.z, ca0.w, ca1.x, ca1.y, ca1.z, ca1.w };
    uint4 o;
    unsigned int* op = (unsigned int*)&o;
    #pragma unroll
    for (int i = 0; i < 4; i++) {
        const unsigned int lo = f2bf(acc[2 * i] * cav[2 * i]);
        const unsigned int hi = f2bf(acc[2 * i + 1] * cav[2 * i + 1]);
        op[i] = lo | (hi << 16);
    }
    *(uint4*)(X + (size_t)q * KDIM + pb * 64 + lane * 8) = o;
}

// ---------------------------------------------------------------------------
// Kernel 3: part[z] = X(MPAD,8192) @ Wtb(256,8192)^T — no-LDS streaming MFMA.
// Both operands K-contiguous: per-lane dwordx4 fragment loads (16 rows x full
// 64B lines per instr), L2-served reuse (X 4x, Wtb 32x). No barriers.
// grid (32, 4, SPLITK) = 1024 blocks. X rows >= NQ hold poison: only
// pollutes part rows >= NQ, which reduce never reads.
// ---------------------------------------------------------------------------
__global__ __launch_bounds__(256) void gemm_kernel(
    const unsigned short* __restrict__ X,    // (MPAD, 8192) bf16
    const unsigned short* __restrict__ Wt,   // (256, 8192) bf16
    float* __restrict__ part)                // (SPLITK, MPAD, 256)
{
    const int m0 = blockIdx.x * 64;
    const int n0 = blockIdx.y * 64;
    const int z  = blockIdx.z;
    const int t  = threadIdx.x;
    const int w    = t >> 6;
    const int lane = t & 63;
    const int mw = (w & 1) * 32;
    const int nw = (w >> 1) * 32;
    const int quad = lane >> 4;
    const int l16  = lane & 15;

    const unsigned short* ar0 = X  + (size_t)(m0 + mw + l16) * KDIM + quad * 8;
    const unsigned short* ar1 = ar0 + (size_t)16 * KDIM;
    const unsigned short* br0 = Wt + (size_t)(n0 + nw + l16) * KDIM + quad * 8;
    const unsigned short* br1 = br0 + (size_t)16 * KDIM;

    f32x4 acc[2][2] = {};
    const int kbase = z * (KDIM / SPLITK);
    #pragma unroll 4
    for (int k = kbase; k < kbase + KDIM / SPLITK; k += 32) {
        const bf16x8 a0 = *(const bf16x8*)(ar0 + k);
        const bf16x8 a1 = *(const bf16x8*)(ar1 + k);
        const bf16x8 b0 = *(const bf16x8*)(br0 + k);
        const bf16x8 b1 = *(const bf16x8*)(br1 + k);
        acc[0][0] = __builtin_amdgcn_mfma_f32_16x16x32_bf16(a0, b0, acc[0][0], 0, 0, 0);
        acc[0][1] = __builtin_amdgcn_mfma_f32_16x16x32_bf16(a0, b1, acc[0][1], 0, 0, 0);
        acc[1][0] = __builtin_amdgcn_mfma_f32_16x16x32_bf16(a1, b0, acc[1][0], 0, 0, 0);
        acc[1][1] = __builtin_amdgcn_mfma_f32_16x16x32_bf16(a1, b1, acc[1][1], 0, 0, 0);
    }

    float* pz = part + (size_t)z * MPAD * EMB;
    #pragma unroll
    for (int i = 0; i < 2; i++)
        #pragma unroll
        for (int j = 0; j < 2; j++) {
            const int n = n0 + nw + 16 * j + l16;
            #pragma unroll
            for (int r = 0; r < 4; r++) {
                const int m = m0 + mw + 16 * i + quad * 4 + r;
                pz[(size_t)m * EMB + n] = acc[i][j][r];
            }
        }
}

// ---------------------------------------------------------------------------
// Kernel 4: out = sum_z part[z] + bias + qc   (fp32, float4)
// ---------------------------------------------------------------------------
__global__ __launch_bounds__(256) void reduce_kernel(
    const float* __restrict__ part, const float* __restrict__ qc,
    const float* __restrict__ bias, float* __restrict__ out)
{
    const int idx = blockIdx.x * 256 + threadIdx.x;
    if (idx >= NQ * 64) return;
    const int m  = idx >> 6;
    const int c4 = idx & 63;
    float4 a = ((const float4*)bias)[c4];
    const float4 qv = ((const float4*)qc)[(size_t)m * 64 + c4];
    a.x += qv.x; a.y += qv.y; a.z += qv.z; a.w += qv.w;
    #pragma unroll
    for (int z = 0; z < SPLITK; z++) {
        const float4 p = ((const float4*)part)[((size_t)z * MPAD + m) * 64 + c4];
        a.x += p.x; a.y += p.y; a.z += p.z; a.w += p.w;
    }
    ((float4*)out)[(size_t)m * 64 + c4] = a;
}

// ---------------------------------------------------------------------------
extern "C" void kernel_launch(void* const* d_in, const int* in_sizes, int n_in,
                              void* d_out, int out_size, void* d_ws, size_t ws_size,
                              hipStream_t stream) {
    (void)in_sizes; (void)n_in; (void)out_size; (void)ws_size;
    const float* v0    = (const float*)d_in[0];
    const float* v1    = (const float*)d_in[1];
    const float* v2    = (const float*)d_in[2];
    const float* v3    = (const float*)d_in[3];
    const float* qc    = (const float*)d_in[4];
    const float* xyzrt = (const float*)d_in[5];
    const float* Woff  = (const float*)d_in[7];
    const float* boff  = (const float*)d_in[8];
    const float* Wca1  = (const float*)d_in[9];
    const float* Wca2  = (const float*)d_in[10];
    const float* Wsa1  = (const float*)d_in[11];
    const float* Wsa2  = (const float*)d_in[12];
    const float* Wout  = (const float*)d_in[13];
    const float* bout  = (const float*)d_in[14];
    float* out = (float*)d_out;

    // ws layout (bytes):
    char* p = (char*)d_ws;
    float* qdata = (float*)p;                 p += (size_t)NQ * 1024 * 4;           //  8.19 MB
    unsigned short* Xb = (unsigned short*)p;  p += (size_t)MPAD * KDIM * 2;         // 33.55 MB
    unsigned short* vt0 = (unsigned short*)p; p += (size_t)2 * 256 * 256 * 256 * 2; // 67.1 MB
    unsigned short* vt1 = (unsigned short*)p; p += (size_t)2 * 128 * 128 * 256 * 2; // 16.8 MB
    unsigned short* vt2 = (unsigned short*)p; p += (size_t)2 * 64 * 64 * 256 * 2;   //  4.2 MB
    unsigned short* vt3 = (unsigned short*)p; p += (size_t)2 * 32 * 32 * 256 * 2;   //  1.05 MB
    unsigned short* Wtb = (unsigned short*)p; p += (size_t)EMB * KDIM * 2;          //  4.2 MB
    float* partb = (float*)p;                 p += (size_t)SPLITK * MPAD * EMB * 4; // 16.8 MB
    float* Hbuf = (float*)p;                  p += (size_t)MPAD * 512 * 4;          //  4.2 MB
    unsigned short* qcH = (unsigned short*)p; p += (size_t)MPAD * 256 * 2;          //  1.05 MB
    unsigned short* qcL = (unsigned short*)p; p += (size_t)MPAD * 256 * 2;          //  1.05 MB
    unsigned short* WHb = (unsigned short*)p; p += (size_t)512 * 256 * 2;           //  0.26 MB
    unsigned short* WLb = (unsigned short*)p;                                        //  0.26 MB

    trans_kernel<<<26368, 256, 0, stream>>>(v0, v1, v2, v3, vt0, vt1, vt2, vt3,
                                            Wout, Wtb, Woff, Wca1, Wsa1,
                                            WHb, WLb, qc, qcH, qcL);
    gemmA_kernel<<<dim3(MPAD / 64, 8), 256, 0, stream>>>(qcH, qcL, WHb, WLb, Hbuf);
    finish_kernel<<<NQ / 8, 256, 0, stream>>>(Hbuf, xyzrt, boff, Wca2, Wsa2, qdata);
    sample_kernel<<<(NQ * 128) / (4 * 8), 256, 0, stream>>>(vt0, vt1, vt2, vt3, qdata, Xb);
    gemm_kernel<<<dim3(MPAD / 64, EMB / 64, SPLITK), 256, 0, stream>>>(Xb, Wtb, partb);
    reduce_kernel<<<(NQ * 64 + 255) / 256, 256, 0, stream>>>(partb, qc, bout, out);
}